// Round 5
// baseline (6668.238 us; speedup 1.0000x reference)
//
#include <hip/hip_runtime.h>
#include <stdint.h>

#define LOG2E 1.44269504088896340736f

struct LtcArgs {
  const float *x, *c1w, *c1b, *c2w, *c2b;
  const float *g1,*vl1,*cm1,*sg1,*mu1,*w1,*er1,*ssg1,*smu1,*sw1,*ser1,*iw1,*ib1,*ow1,*ob1;
  const void  *mk1,*smk1;
  const float *g2,*vl2,*cm2,*sg2,*mu2,*w2,*er2,*ssg2,*smu2,*sw2,*ser2,*iw2,*ib2,*ow2,*ob2;
  const void  *mk2,*smk2;
  const float *fcw,*fcb;
  float *out;
};

__device__ __forceinline__ float fexp2(float v){ return __builtin_amdgcn_exp2f(v); }
__device__ __forceinline__ float frcp (float v){ return __builtin_amdgcn_rcpf(v); }
// per-lane variable gather within the wave (ds_bpermute)
__device__ __forceinline__ float gather(float v, int srcLane){
  return __int_as_float(__builtin_amdgcn_ds_bpermute(srcLane<<2, __float_as_int(v)));
}
__device__ __forceinline__ int wave_max(int v){
  #pragma unroll
  for (int s=1;s<64;s<<=1){ int o=__shfl_xor(v,s); v = o>v ? o : v; }
  return __builtin_amdgcn_readfirstlane(v);
}

// ---- mask dtype detection (verified R1-R4: absmax 0) ----
__device__ __forceinline__ void scan_mask(const void* p, int n, int tid, int* cge2, int* cone){
  const uint8_t* bp = (const uint8_t*)p;
  int g=0,o=0;
  for (int k=tid;k<n;k+=256){ uint8_t v=bp[k]; g += (v>=2); o += (v==1); }
  if (g) atomicAdd(cge2,g);
  if (o) atomicAdd(cone,o);
}
__device__ __forceinline__ int decide_mode(int ge2,int one,int n){
  if (ge2 > (n>>4)) return 2;
  if (one > (n>>2)) return 0;
  return 1;
}
__device__ __forceinline__ float mask_at(const void* p,int mode,int idx){
  if (mode==2) return ((const float*)p)[idx]!=0.f ? 1.f:0.f;
  if (mode==1) return ((const int*)p)[idx]!=0 ? 1.f:0.f;
  return ((const uint8_t*)p)[idx]!=0 ? 1.f:0.f;
}

// ================= kernel 0: mask modes -> hdr =================
__global__ void ltc_modes(const void* mk1,const void* smk1,const void* mk2,const void* smk2,int* hdr){
  __shared__ int cnt[8];
  const int tid=threadIdx.x;
  if (tid<8) cnt[tid]=0;
  __syncthreads();
  scan_mask(mk1, 4096, tid, &cnt[0], &cnt[1]);
  scan_mask(smk1,2048, tid, &cnt[2], &cnt[3]);
  scan_mask(mk2, 1024, tid, &cnt[4], &cnt[5]);
  scan_mask(smk2,1024, tid, &cnt[6], &cnt[7]);
  __syncthreads();
  if (tid==0){
    hdr[0]=decide_mode(cnt[0],cnt[1],4096);
    hdr[1]=decide_mode(cnt[2],cnt[3],2048);
    hdr[2]=decide_mode(cnt[4],cnt[5],1024);
    hdr[3]=decide_mode(cnt[6],cnt[7],1024);
  }
}

// ================= kernel 1: precompute conv + L1 synapse sums =================
__global__ __launch_bounds__(256,2)
void ltc_pre(LtcArgs a, const int* __restrict__ hdr, float2* __restrict__ pre)
{
  const int b=blockIdx.x, tb=blockIdx.y*64, tid=threadIdx.x;
  const int mds1=hdr[1];
  __shared__ float us[4][32];

  const int j = tid&63;
  float As[32],Bs[32],Ws[32],Es[32];
  #pragma unroll
  for (int e=0;e<32;e++){
    const int idx=e*64+j;
    const float s=a.ssg1[idx];
    As[e]=-s*LOG2E; Bs[e]=s*a.smu1[idx]*LOG2E;
    const float wm=a.sw1[idx]*mask_at(a.smk1,mds1,idx);
    Ws[e]=wm; Es[e]=wm*a.ser1[idx];
  }
  const int th=tid>>5, f=tid&31, cc=f>>2, cwp=f&3;
  float k1[12],b1[4],k2[12],cb2=0.f,wi=0.f,bi=0.f;
  if (tid<128){
    #pragma unroll
    for (int q=0;q<12;q++) k1[q]=a.c1w[q];
    #pragma unroll
    for (int q=0;q<4;q++)  b1[q]=a.c1b[q];
    #pragma unroll
    for (int q=0;q<12;q++) k2[q]=a.c2w[cc*12+q];
    cb2=a.c2b[cc]; wi=a.iw1[f]; bi=a.ib1[f];
  }

  for (int tt=0; tt<64; tt+=4){
    if (tid<128){
      const int t=tb+tt+th;
      const float4* xg=(const float4*)(a.x + ((size_t)b*1024 + t)*8);
      float4 xa=xg[0], xb=xg[1];
      float xr[8]={xa.x,xa.y,xa.z,xa.w,xb.x,xb.y,xb.z,xb.w};
      float acc=cb2;
      #pragma unroll
      for (int ci=0;ci<4;ci++){
        const float q0=k1[ci*3],q1=k1[ci*3+1],q2=k1[ci*3+2],bb=b1[ci];
        #pragma unroll
        for (int kk=0;kk<3;kk++){
          const int p=cwp+kk;
          float h=fmaf(q0,xr[p],fmaf(q1,xr[p+1],fmaf(q2,xr[p+2],bb)));
          h=fmaxf(h,0.f);
          acc=fmaf(k2[ci*3+kk],h,acc);
        }
      }
      us[th][f]=fmaf(acc,wi,bi);
    }
    __syncthreads();
    {
      const int t4=tid>>6;
      float wns=0.f,wds=0.f;
      #pragma unroll
      for (int e=0;e<32;e++){
        const float u=us[t4][e];
        const float z=fmaf(As[e],u,Bs[e]);
        const float sg=frcp(1.f+fexp2(z));
        wds=fmaf(Ws[e],sg,wds);
        wns=fmaf(Es[e],sg,wns);
      }
      pre[((size_t)((b<<10)+tb+tt+t4))*64 + j] = make_float2(wns,wds);
    }
    __syncthreads();
  }
}

// ================= kernel 2: scan with decoupled wave-groups =================
// 256 blocks x 384 thr (6 waves). Waves 0-3: L1 with private LDS soft-barrier
// (weighted slot partition). Waves 4-5: L2, one step behind, private 2-wave
// soft-barrier. Handoff via v1ring + monotone tokens. NO s_barrier in loop.
__global__ __launch_bounds__(384,1)
void ltc_scan(LtcArgs a, const float2* __restrict__ pre, const int* __restrict__ hdr)
{
  const int b=blockIdx.x, tid=threadIdx.x;
  const int w=tid>>6, l=tid&63;

  __shared__ float2 p1[2][4][64];
  __shared__ float2 p2x[2][2][32];
  __shared__ float2 pbx[2][32];
  __shared__ float  v1ring[8][64];
  __shared__ int    barA[4];
  __shared__ int    barB[2];
  __shared__ int    tokStep;
  __shared__ int    tokAck;

  volatile int* vbarA = barA;
  volatile int* vbarB = barB;
  volatile int* vtokStep = &tokStep;
  volatile int* vtokAck  = &tokAck;

  if (tid<4) barA[tid]=0;
  if (tid<2) barB[tid]=0;
  if (tid==0){ tokStep=0; tokAck=0; }
  __syncthreads();   // the ONLY full barrier

  const int md1=hdr[0], md2=hdr[2], mds2=hdr[3];

  if (w<4){
    // ================= L1 group =================
    const int NS=20;
    float A[NS],B[NS],W[NS],E[NS]; int I[NS];
    #pragma unroll
    for (int q=0;q<NS;q++){ A[q]=0.f;B[q]=0.f;W[q]=0.f;E[q]=0.f;I[q]=0; }
    int cnt=0;
    {
      unsigned long long mm=0ull;
      for (int e=0;e<64;e++)
        if (mask_at(a.mk1,md1,e*64+l)!=0.f) mm |= (1ull<<e);
      int r=0;
      while (mm){
        const int e=(int)__builtin_ctzll(mm); mm&=mm-1;
        const int r8=r&7;
        // rank->wave pattern per 8: {0,2,3,2,3,2,3,1}
        const int rw = (r8==0) ? 0 : ((r8==7) ? 1 : ((r8&1)?2:3));
        if (rw==w && cnt<NS){
          const int idx=e*64+l;
          const float s=a.sg1[idx];
          A[cnt]=-s*LOG2E; B[cnt]=s*a.mu1[idx]*LOG2E;
          const float wmv=a.w1[idx];
          W[cnt]=wmv; E[cnt]=wmv*a.er1[idx];
          I[cnt]=e;
          cnt++;
        }
        r++;
      }
    }
    const int c1max = wave_max(cnt);
    const float cmt=a.cm1[l]*6.f, gl=a.g1[l], gv=gl*a.vl1[l];
    float2 cur = pre[((size_t)(b<<10))*64 + l], nxt=make_float2(0.f,0.f);
    float v1=0.f, bn=0.f, bdb=1.f;
    int segA=0;

    #pragma unroll 1
    for (int t=0;t<1024;t++){
      #pragma unroll
      for (int k=0;k<6;k++){
        segA++;
        float sn0=0.f,sn1=0.f,sd0=0.f,sd1=0.f;
        #pragma unroll
        for (int q=0;q<NS;q++){
          if (q<2 || q<c1max){
            const float vv=gather(v1, I[q]);
            const float z=fmaf(A[q],vv,B[q]);
            const float sg=frcp(1.f+fexp2(z));
            if (q&1){ sd1=fmaf(W[q],sg,sd1); sn1=fmaf(E[q],sg,sn1); }
            else    { sd0=fmaf(W[q],sg,sd0); sn0=fmaf(E[q],sg,sn0); }
          }
        }
        const int buf=k&1;
        p1[buf][w][l]=make_float2(sn0+sn1,sd0+sd1);
        asm volatile("s_waitcnt lgkmcnt(0)" ::: "memory");
        if (l==0) vbarA[w]=segA;
        {
          int val=vbarA[l&3];
          while (__ballot(val>=segA)!=~0ull){ __builtin_amdgcn_s_sleep(1); val=vbarA[l&3]; }
        }
        asm volatile("" ::: "memory");
        if (k==0){
          bn = gv + cur.x;
          bdb = cmt + gl + cur.y + 1e-8f;
          if (t+1<1024) nxt = pre[((size_t)((b<<10)+t+1))*64 + l];
        }
        const float2 q0=p1[buf][0][l], q1=p1[buf][1][l], q2=p1[buf][2][l], q3=p1[buf][3][l];
        v1 = (fmaf(cmt,v1,bn)+((q0.x+q1.x)+(q2.x+q3.x)))
             * frcp(bdb+((q0.y+q1.y)+(q2.y+q3.y)));
        if (k==5){
          if (w==0){
            if (t>=8){
              int av=*vtokAck;
              while (av < t-7){ __builtin_amdgcn_s_sleep(2); av=*vtokAck; }
            }
            v1ring[t&7][l]=v1;
            asm volatile("s_waitcnt lgkmcnt(0)" ::: "memory");
            if (l==0) *vtokStep = t+1;
          }
          cur=nxt;
        }
      }
    }
  } else {
    // ================= L2 group ================= (waves 4,5)
    const int wv=w-4, j=l&31, p=(wv<<1)+(l>>5);
    float A2[8],B2[8],W2[8],E2[8]; int I2[8];
    float As2[8],Bs2[8],Ws2[8],Es2[8]; int Is2[8];
    #pragma unroll
    for (int q=0;q<8;q++){ A2[q]=0.f;B2[q]=0.f;W2[q]=0.f;E2[q]=0.f;I2[q]=0;
                           As2[q]=0.f;Bs2[q]=0.f;Ws2[q]=0.f;Es2[q]=0.f;Is2[q]=0; }
    int cntm=0, cnts=0;
    { // main synapse (mk2): part p takes ranks == p (mod 4); 8 slots covers nnz<=32
      unsigned mm=0u;
      for (int e=0;e<32;e++)
        if (mask_at(a.mk2,md2,e*32+j)!=0.f) mm |= (1u<<e);
      int r=0;
      while (mm){
        const int e=(int)__builtin_ctz(mm); mm&=mm-1;
        if ((r&3)==p && cntm<8){
          const int idx=e*32+j;
          const float s=a.sg2[idx];
          A2[cntm]=-s*LOG2E; B2[cntm]=s*a.mu2[idx]*LOG2E;
          const float wmv=a.w2[idx];
          W2[cntm]=wmv; E2[cntm]=wmv*a.er2[idx];
          I2[cntm]=e;
          cntm++;
        }
        r++;
      }
    }
    { // sensory synapse (smk2), input-affine folded (verified R4)
      unsigned mm=0u;
      for (int e=0;e<32;e++)
        if (mask_at(a.smk2,mds2,e*32+j)!=0.f) mm |= (1u<<e);
      int r=0;
      while (mm){
        const int e=(int)__builtin_ctz(mm); mm&=mm-1;
        if ((r&3)==p && cnts<8){
          const int idx=e*32+j;
          const float s=a.ssg2[idx];
          float Aq=-s*LOG2E, Bq=s*a.smu2[idx]*LOG2E;
          const float wi=a.ow1[e]*a.iw2[e];
          const float ci=fmaf(a.ob1[e],a.iw2[e],a.ib2[e]);
          Bq=fmaf(Aq,ci,Bq); Aq*=wi;
          As2[cnts]=Aq; Bs2[cnts]=Bq;
          const float wmv=a.sw2[idx];
          Ws2[cnts]=wmv; Es2[cnts]=wmv*a.ser2[idx];
          Is2[cnts]=e;
          cnts++;
        }
        r++;
      }
    }
    const int c2max = wave_max(cntm);
    const int c2smax = wave_max(cnts);
    const float cmt=a.cm2[j]*6.f, gl=a.g2[j], gv=gl*a.vl2[j];
    float v2=0.f, bn=0.f, bdb=1.f;
    int segB=0;

    #pragma unroll 1
    for (int s=1;s<=1024;s++){
      { int tv=*vtokStep;
        while (tv<s){ __builtin_amdgcn_s_sleep(2); tv=*vtokStep; } }
      asm volatile("" ::: "memory");
      // sensory sums from v1(s-1)
      float ssn=0.f,ssd=0.f;
      const float* vrow = &v1ring[(s-1)&7][0];
      #pragma unroll
      for (int q=0;q<8;q++){
        if (q<2 || q<c2smax){
          const float vb=vrow[Is2[q]];
          const float z=fmaf(As2[q],vb,Bs2[q]);
          const float sg=frcp(1.f+fexp2(z));
          ssd=fmaf(Ws2[q],sg,ssd); ssn=fmaf(Es2[q],sg,ssn);
        }
      }
      ssn += __shfl_xor(ssn,32); ssd += __shfl_xor(ssd,32);
      if (l<32) pbx[wv][j]=make_float2(ssn,ssd);
      #pragma unroll
      for (int k=0;k<6;k++){
        segB++;
        float sn=0.f,sd=0.f;
        #pragma unroll
        for (int q=0;q<8;q++){
          if (q<2 || q<c2max){
            const float vv=gather(v2, I2[q]);
            const float z=fmaf(A2[q],vv,B2[q]);
            const float sg=frcp(1.f+fexp2(z));
            sd=fmaf(W2[q],sg,sd); sn=fmaf(E2[q],sg,sn);
          }
        }
        sn += __shfl_xor(sn,32); sd += __shfl_xor(sd,32);
        const int buf=k&1;
        if (l<32) p2x[buf][wv][j]=make_float2(sn,sd);
        asm volatile("s_waitcnt lgkmcnt(0)" ::: "memory");
        if (l==0) vbarB[wv]=segB;
        {
          int val=vbarB[l&1];
          while (__ballot(val>=segB)!=~0ull){ __builtin_amdgcn_s_sleep(1); val=vbarB[l&1]; }
        }
        asm volatile("" ::: "memory");
        if (k==0){
          const float2 pb0=pbx[0][j], pb1=pbx[1][j];
          bn = gv + pb0.x + pb1.x;
          bdb = cmt + gl + pb0.y + pb1.y + 1e-8f;
        }
        const float2 o = p2x[buf][wv^1][j];
        v2 = (fmaf(cmt,v2,bn)+(sn+o.x)) * frcp(bdb+(sd+o.y));
      }
      if (w==4 && l==0){
        asm volatile("s_waitcnt lgkmcnt(0)" ::: "memory");
        *vtokAck = s;
      }
    }

    // epilogue: lanes 0..15 of wave 4 hold v2[0..15]
    if (w==4 && l<16){
      float o = fmaf(v2, a.ow2[l], a.ob2[l]) * a.fcw[l];
      o += __shfl_xor(o,1); o += __shfl_xor(o,2); o += __shfl_xor(o,4); o += __shfl_xor(o,8);
      if (l==0){
        const float z = o + a.fcb[0];
        a.out[b] = frcp(1.f + fexp2(-z*LOG2E));
      }
    }
  }
}

// ================= fallback: R1 fused kernel (verified) =================
__global__ __launch_bounds__(256,1)
void ltc_fused(LtcArgs a)
{
  const int b=blockIdx.x, tid=threadIdx.x;
  __shared__ __align__(16) float xs[8192];
  __shared__ __align__(16) float v1s[2][64];
  __shared__ __align__(16) float v2s[2][32];
  __shared__ __align__(16) float u1s[8][32];
  __shared__ float cwts[184];
  __shared__ int cnt[8];

  {
    const float4* xg=(const float4*)(a.x + (size_t)b*8192);
    float4* xd=(float4*)xs;
    #pragma unroll
    for (int k=0;k<8;k++) xd[tid+256*k]=xg[tid+256*k];
  }
  if (tid<8) cnt[tid]=0;
  if (tid<64){ v1s[0][tid]=0.f; v1s[1][tid]=0.f; }
  if (tid<32){ v2s[0][tid]=0.f; v2s[1][tid]=0.f; }
  if (tid<12) cwts[tid]=a.c1w[tid];
  else if (tid<16)  cwts[tid]=a.c1b[tid-12];
  else if (tid<112) cwts[tid]=a.c2w[tid-16];
  else if (tid<120) cwts[tid]=a.c2b[tid-112];
  else if (tid<152) cwts[tid]=a.iw1[tid-120];
  else if (tid<184) cwts[tid]=a.ib1[tid-152];
  __syncthreads();

  scan_mask(a.mk1, 4096, tid, &cnt[0], &cnt[1]);
  scan_mask(a.smk1,2048, tid, &cnt[2], &cnt[3]);
  scan_mask(a.mk2, 1024, tid, &cnt[4], &cnt[5]);
  scan_mask(a.smk2,1024, tid, &cnt[6], &cnt[7]);
  __syncthreads();
  const int md1 =decide_mode(cnt[0],cnt[1],4096);
  const int mds1=decide_mode(cnt[2],cnt[3],2048);
  const int md2 =decide_mode(cnt[4],cnt[5],1024);
  const int mds2=decide_mode(cnt[6],cnt[7],1024);

  const int j1=tid>>2, ig1=tid&3;
  float Au[16],Bu[16],Wu[16],Eu[16];
  #pragma unroll
  for (int e=0;e<16;e++){
    const int i=16*ig1+e, idx=i*64+j1;
    const float s=a.sg1[idx];
    Au[e]=-s*LOG2E; Bu[e]=s*a.mu1[idx]*LOG2E;
    const float wm=a.w1[idx]*mask_at(a.mk1,md1,idx);
    Wu[e]=wm; Eu[e]=wm*a.er1[idx];
  }
  float As[8],Bs[8],Ws[8],Es[8];
  #pragma unroll
  for (int e=0;e<8;e++){
    const int i=8*ig1+e, idx=i*64+j1;
    const float s=a.ssg1[idx];
    As[e]=-s*LOG2E; Bs[e]=s*a.smu1[idx]*LOG2E;
    const float wm=a.sw1[idx]*mask_at(a.smk1,mds1,idx);
    Ws[e]=wm; Es[e]=wm*a.ser1[idx];
  }
  const float cmt1=a.cm1[j1]*6.f, gl1=a.g1[j1], gv1=gl1*a.vl1[j1];

  const int j2=tid>>3, ig2=tid&7;
  float A2[4],B2[4],W2[4],E2[4],A2s[4],B2s[4],W2s[4],E2s[4],Wi2[4],Ci2[4];
  #pragma unroll
  for (int e=0;e<4;e++){
    const int i=4*ig2+e, idx=i*32+j2;
    { const float s=a.sg2[idx];
      A2[e]=-s*LOG2E; B2[e]=s*a.mu2[idx]*LOG2E;
      const float wm=a.w2[idx]*mask_at(a.mk2,md2,idx);
      W2[e]=wm; E2[e]=wm*a.er2[idx]; }
    { const float s=a.ssg2[idx];
      A2s[e]=-s*LOG2E; B2s[e]=s*a.smu2[idx]*LOG2E;
      const float wm=a.sw2[idx]*mask_at(a.smk2,mds2,idx);
      W2s[e]=wm; E2s[e]=wm*a.ser2[idx]; }
    Wi2[e]=a.ow1[i]*a.iw2[i];
    Ci2[e]=fmaf(a.ob1[i],a.iw2[i],a.ib2[i]);
  }
  const float cmt2=a.cm2[j2]*6.f, gl2=a.g2[j2], gv2=gl2*a.vl2[j2];

  float vj1=0.f, vj2=0.f;
  int p1x=0, p2x=0;
  const int cf=tid&31, cc=cf>>2, cwp=cf&3, ctc=tid>>5;

  for (int t=0;t<1024;t++){
    if ((t&7)==0){
      const float* xr = &xs[(t+ctc)*8];
      float acc = cwts[112+cc];
      #pragma unroll
      for (int ci=0;ci<4;ci++){
        const float k10=cwts[ci*3], k11=cwts[ci*3+1], k12=cwts[ci*3+2], bb=cwts[12+ci];
        #pragma unroll
        for (int kk=0;kk<3;kk++){
          const int p=cwp+kk;
          float h = fmaf(k10,xr[p], fmaf(k11,xr[p+1], fmaf(k12,xr[p+2], bb)));
          h = fmaxf(h,0.f);
          acc = fmaf(cwts[16+(cc*4+ci)*3+kk], h, acc);
        }
      }
      u1s[ctc][cf] = fmaf(acc, cwts[120+cf], cwts[152+cf]);
      __syncthreads();
    }

    float wns=0.f, wds=0.f;
    {
      const float4* uv4=(const float4*)&u1s[t&7][8*ig1];
      float4 qa=uv4[0], qb=uv4[1];
      float uvv[8]={qa.x,qa.y,qa.z,qa.w,qb.x,qb.y,qb.z,qb.w};
      #pragma unroll
      for (int e=0;e<8;e++){
        float z=fmaf(As[e],uvv[e],Bs[e]);
        float sg=frcp(1.f+fexp2(z));
        wds=fmaf(Ws[e],sg,wds);
        wns=fmaf(Es[e],sg,wns);
      }
      wns += __shfl_xor(wns,1); wns += __shfl_xor(wns,2);
      wds += __shfl_xor(wds,1); wds += __shfl_xor(wds,2);
    }
    const float bn1 = gv1 + wns;
    const float bd1 = cmt1 + gl1 + wds + 1e-8f;

    #pragma unroll
    for (int k=0;k<6;k++){
      const float4* vv4=(const float4*)&v1s[p1x][16*ig1];
      float4 q0=vv4[0], q1=vv4[1], q2=vv4[2], q3=vv4[3];
      float vi[16]={q0.x,q0.y,q0.z,q0.w,q1.x,q1.y,q1.z,q1.w,
                    q2.x,q2.y,q2.z,q2.w,q3.x,q3.y,q3.z,q3.w};
      float sn=0.f, sd=0.f;
      #pragma unroll
      for (int e=0;e<16;e++){
        float z=fmaf(Au[e],vi[e],Bu[e]);
        float sg=frcp(1.f+fexp2(z));
        sd=fmaf(Wu[e],sg,sd);
        sn=fmaf(Eu[e],sg,sn);
      }
      sn += __shfl_xor(sn,1); sn += __shfl_xor(sn,2);
      sd += __shfl_xor(sd,1); sd += __shfl_xor(sd,2);
      vj1 = (fmaf(cmt1,vj1,bn1)+sn) * frcp(bd1+sd);
      p1x ^= 1;
      if (ig1==0) v1s[p1x][j1]=vj1;
      __syncthreads();
    }

    float wns2=0.f, wds2=0.f;
    {
      const float4* vf4=(const float4*)&v1s[p1x][4*ig2];
      float4 vf=vf4[0];
      float vin[4]={vf.x,vf.y,vf.z,vf.w};
      #pragma unroll
      for (int e=0;e<4;e++){
        float u2=fmaf(vin[e],Wi2[e],Ci2[e]);
        float z=fmaf(A2s[e],u2,B2s[e]);
        float sg=frcp(1.f+fexp2(z));
        wds2=fmaf(W2s[e],sg,wds2);
        wns2=fmaf(E2s[e],sg,wns2);
      }
      wns2 += __shfl_xor(wns2,1); wns2 += __shfl_xor(wns2,2); wns2 += __shfl_xor(wns2,4);
      wds2 += __shfl_xor(wds2,1); wds2 += __shfl_xor(wds2,2); wds2 += __shfl_xor(wds2,4);
    }
    const float bn2 = gv2 + wns2;
    const float bd2 = cmt2 + gl2 + wds2 + 1e-8f;

    #pragma unroll
    for (int k=0;k<6;k++){
      const float4* vv4=(const float4*)&v2s[p2x][4*ig2];
      float4 q=vv4[0];
      float vi[4]={q.x,q.y,q.z,q.w};
      float sn=0.f, sd=0.f;
      #pragma unroll
      for (int e=0;e<4;e++){
        float z=fmaf(A2[e],vi[e],B2[e]);
        float sg=frcp(1.f+fexp2(z));
        sd=fmaf(W2[e],sg,sd);
        sn=fmaf(E2[e],sg,sn);
      }
      sn += __shfl_xor(sn,1); sn += __shfl_xor(sn,2); sn += __shfl_xor(sn,4);
      sd += __shfl_xor(sd,1); sd += __shfl_xor(sd,2); sd += __shfl_xor(sd,4);
      vj2 = (fmaf(cmt2,vj2,bn2)+sn) * frcp(bd2+sd);
      p2x ^= 1;
      if (ig2==0) v2s[p2x][j2]=vj2;
      __syncthreads();
    }
  }

  if (tid<16){
    float o = fmaf(v2s[p2x][tid], a.ow2[tid], a.ob2[tid]) * a.fcw[tid];
    o += __shfl_xor(o,1); o += __shfl_xor(o,2); o += __shfl_xor(o,4); o += __shfl_xor(o,8);
    if (tid==0){
      float z = o + a.fcb[0];
      a.out[b] = frcp(1.f + fexp2(-z*LOG2E));
    }
  }
}

extern "C" void kernel_launch(void* const* d_in, const int* in_sizes, int n_in,
                              void* d_out, int out_size, void* d_ws, size_t ws_size,
                              hipStream_t stream)
{
  (void)out_size;
  int o[41];
  for (int i=0;i<41;i++) o[i]=i;
  if (n_in>=41 && in_sizes[20]!=4096){
    for (int i=0;i<15;i++) o[5+i]=5+i;
    o[20]=37; o[21]=38;
    for (int i=0;i<15;i++) o[22+i]=20+i;
    o[37]=39; o[38]=40;
    o[39]=35; o[40]=36;
  }
  const float* F[41];
  for (int i=0;i<41;i++) F[i]=(const float*)d_in[o[i]];
  LtcArgs a;
  a.x=F[0]; a.c1w=F[1]; a.c1b=F[2]; a.c2w=F[3]; a.c2b=F[4];
  a.g1=F[5]; a.vl1=F[6]; a.cm1=F[7]; a.sg1=F[8]; a.mu1=F[9]; a.w1=F[10]; a.er1=F[11];
  a.ssg1=F[12]; a.smu1=F[13]; a.sw1=F[14]; a.ser1=F[15];
  a.iw1=F[16]; a.ib1=F[17]; a.ow1=F[18]; a.ob1=F[19];
  a.mk1=(const void*)d_in[o[20]]; a.smk1=(const void*)d_in[o[21]];
  a.g2=F[22]; a.vl2=F[23]; a.cm2=F[24]; a.sg2=F[25]; a.mu2=F[26]; a.w2=F[27]; a.er2=F[28];
  a.ssg2=F[29]; a.smu2=F[30]; a.sw2=F[31]; a.ser2=F[32];
  a.iw2=F[33]; a.ib2=F[34]; a.ow2=F[35]; a.ob2=F[36];
  a.mk2=(const void*)d_in[o[37]]; a.smk2=(const void*)d_in[o[38]];
  a.fcw=F[39]; a.fcb=F[40];
  a.out=(float*)d_out;

  const size_t need = 256 + (size_t)256*1024*64*sizeof(float2);
  if (ws_size >= need){
    int* hdr = (int*)d_ws;
    float2* pre = (float2*)((char*)d_ws + 256);
    ltc_modes<<<dim3(1),dim3(256),0,stream>>>(a.mk1,a.smk1,a.mk2,a.smk2,hdr);
    ltc_pre<<<dim3(256,16),dim3(256),0,stream>>>(a,hdr,pre);
    ltc_scan<<<dim3(256),dim3(384),0,stream>>>(a,pre,hdr);
  } else {
    ltc_fused<<<dim3(256),dim3(256),0,stream>>>(a);
  }
}

// Round 6
// 3521.416 us; speedup vs baseline: 1.8936x; 1.8936x over previous
//
#include <hip/hip_runtime.h>
#include <stdint.h>

#define LOG2E 1.44269504088896340736f

struct LtcArgs {
  const float *x, *c1w, *c1b, *c2w, *c2b;
  const float *g1,*vl1,*cm1,*sg1,*mu1,*w1,*er1,*ssg1,*smu1,*sw1,*ser1,*iw1,*ib1,*ow1,*ob1;
  const void  *mk1,*smk1;
  const float *g2,*vl2,*cm2,*sg2,*mu2,*w2,*er2,*ssg2,*smu2,*sw2,*ser2,*iw2,*ib2,*ow2,*ob2;
  const void  *mk2,*smk2;
  const float *fcw,*fcb;
  float *out;
};

__device__ __forceinline__ float fexp2(float v){ return __builtin_amdgcn_exp2f(v); }
__device__ __forceinline__ float frcp (float v){ return __builtin_amdgcn_rcpf(v); }
// per-lane variable gather within the wave (ds_bpermute)
__device__ __forceinline__ float gather(float v, int srcLane){
  return __int_as_float(__builtin_amdgcn_ds_bpermute(srcLane<<2, __float_as_int(v)));
}
__device__ __forceinline__ int wave_max(int v){
  #pragma unroll
  for (int s=1;s<64;s<<=1){ int o=__shfl_xor(v,s); v = o>v ? o : v; }
  return __builtin_amdgcn_readfirstlane(v);
}

// ---- mask dtype detection (verified R1-R5: absmax 0) ----
__device__ __forceinline__ void scan_mask(const void* p, int n, int tid, int* cge2, int* cone){
  const uint8_t* bp = (const uint8_t*)p;
  int g=0,o=0;
  for (int k=tid;k<n;k+=256){ uint8_t v=bp[k]; g += (v>=2); o += (v==1); }
  if (g) atomicAdd(cge2,g);
  if (o) atomicAdd(cone,o);
}
__device__ __forceinline__ int decide_mode(int ge2,int one,int n){
  if (ge2 > (n>>4)) return 2;
  if (one > (n>>2)) return 0;
  return 1;
}
__device__ __forceinline__ float mask_at(const void* p,int mode,int idx){
  if (mode==2) return ((const float*)p)[idx]!=0.f ? 1.f:0.f;
  if (mode==1) return ((const int*)p)[idx]!=0 ? 1.f:0.f;
  return ((const uint8_t*)p)[idx]!=0 ? 1.f:0.f;
}

// ================= kernel 0: mask modes -> hdr =================
__global__ void ltc_modes(const void* mk1,const void* smk1,const void* mk2,const void* smk2,int* hdr){
  __shared__ int cnt[8];
  const int tid=threadIdx.x;
  if (tid<8) cnt[tid]=0;
  __syncthreads();
  scan_mask(mk1, 4096, tid, &cnt[0], &cnt[1]);
  scan_mask(smk1,2048, tid, &cnt[2], &cnt[3]);
  scan_mask(mk2, 1024, tid, &cnt[4], &cnt[5]);
  scan_mask(smk2,1024, tid, &cnt[6], &cnt[7]);
  __syncthreads();
  if (tid==0){
    hdr[0]=decide_mode(cnt[0],cnt[1],4096);
    hdr[1]=decide_mode(cnt[2],cnt[3],2048);
    hdr[2]=decide_mode(cnt[4],cnt[5],1024);
    hdr[3]=decide_mode(cnt[6],cnt[7],1024);
  }
}

// ================= kernel 1: precompute conv + L1 synapse sums =================
__global__ __launch_bounds__(256,2)
void ltc_pre(LtcArgs a, const int* __restrict__ hdr, float2* __restrict__ pre)
{
  const int b=blockIdx.x, tb=blockIdx.y*64, tid=threadIdx.x;
  const int mds1=hdr[1];
  __shared__ float us[4][32];

  const int j = tid&63;
  float As[32],Bs[32],Ws[32],Es[32];
  #pragma unroll
  for (int e=0;e<32;e++){
    const int idx=e*64+j;
    const float s=a.ssg1[idx];
    As[e]=-s*LOG2E; Bs[e]=s*a.smu1[idx]*LOG2E;
    const float wm=a.sw1[idx]*mask_at(a.smk1,mds1,idx);
    Ws[e]=wm; Es[e]=wm*a.ser1[idx];
  }
  const int th=tid>>5, f=tid&31, cc=f>>2, cwp=f&3;
  float k1[12],b1[4],k2[12],cb2=0.f,wi=0.f,bi=0.f;
  if (tid<128){
    #pragma unroll
    for (int q=0;q<12;q++) k1[q]=a.c1w[q];
    #pragma unroll
    for (int q=0;q<4;q++)  b1[q]=a.c1b[q];
    #pragma unroll
    for (int q=0;q<12;q++) k2[q]=a.c2w[cc*12+q];
    cb2=a.c2b[cc]; wi=a.iw1[f]; bi=a.ib1[f];
  }

  for (int tt=0; tt<64; tt+=4){
    if (tid<128){
      const int t=tb+tt+th;
      const float4* xg=(const float4*)(a.x + ((size_t)b*1024 + t)*8);
      float4 xa=xg[0], xb=xg[1];
      float xr[8]={xa.x,xa.y,xa.z,xa.w,xb.x,xb.y,xb.z,xb.w};
      float acc=cb2;
      #pragma unroll
      for (int ci=0;ci<4;ci++){
        const float q0=k1[ci*3],q1=k1[ci*3+1],q2=k1[ci*3+2],bb=b1[ci];
        #pragma unroll
        for (int kk=0;kk<3;kk++){
          const int p=cwp+kk;
          float h=fmaf(q0,xr[p],fmaf(q1,xr[p+1],fmaf(q2,xr[p+2],bb)));
          h=fmaxf(h,0.f);
          acc=fmaf(k2[ci*3+kk],h,acc);
        }
      }
      us[th][f]=fmaf(acc,wi,bi);
    }
    __syncthreads();
    {
      const int t4=tid>>6;
      float wns=0.f,wds=0.f;
      #pragma unroll
      for (int e=0;e<32;e++){
        const float u=us[t4][e];
        const float z=fmaf(As[e],u,Bs[e]);
        const float sg=frcp(1.f+fexp2(z));
        wds=fmaf(Ws[e],sg,wds);
        wns=fmaf(Es[e],sg,wns);
      }
      pre[((size_t)((b<<10)+tb+tt+t4))*64 + j] = make_float2(wns,wds);
    }
    __syncthreads();
  }
}

// ================= kernel 2: sequential scan, mask-compacted, branch-free =================
// 256 blocks x 512 thr. Waves 0-3: L1 (lane=neuron, 11 unconditional compacted
// slots + rare guarded tail). Waves 4-7: L2 pipelined one step behind, 4
// unconditional slots. s_barrier per segment (verified cheap vs soft barrier).
__global__ __launch_bounds__(512,1)
void ltc_scan(LtcArgs a, const float2* __restrict__ pre, const int* __restrict__ hdr)
{
  const int b=blockIdx.x, tid=threadIdx.x;
  const int w=tid>>6, l=tid&63;
  const bool L1g = (w<4);

  __shared__ float2 p1[2][4][64];    // L1 partials (sn,sd)
  __shared__ float2 p2[2][8][32];    // L2 unfold partials
  __shared__ float2 pb[8][32];       // L2 synapse partials
  __shared__ float  v1buf[64];

  const int md1=hdr[0], md2=hdr[2], mds2=hdr[3];

  // L1 compacted: 16 slots, wave w takes ranks == w (mod 4); zero-padded.
  float A[16],B[16],W[16],E[16]; int I[16];
  // L2 compacted: 4 slots each (ranks == c mod 8 over 32 inputs); zero-padded.
  float A2[4],B2[4],W2[4],E2[4]; int I2[4];
  float As2[4],Bs2[4],Ws2[4],Es2[4]; int Is2[4];
  float cmt,gl,gv;
  int j2=0, c=0;
  int c1max=0;
  float2 cur=make_float2(0.f,0.f), nxt=make_float2(0.f,0.f);

  if (L1g){
    #pragma unroll
    for (int q=0;q<16;q++){ A[q]=0.f;B[q]=0.f;W[q]=0.f;E[q]=0.f;I[q]=0; }
    unsigned long long mm=0ull;
    for (int e=0;e<64;e++)
      if (mask_at(a.mk1,md1,e*64+l)!=0.f) mm |= (1ull<<e);
    int r=0, cnt=0;
    while (mm){
      const int e=(int)__builtin_ctzll(mm); mm&=mm-1;
      if ((r&3)==w && cnt<16){
        const int idx=e*64+l;
        const float s=a.sg1[idx];
        A[cnt]=-s*LOG2E; B[cnt]=s*a.mu1[idx]*LOG2E;
        const float wmv=a.w1[idx];
        W[cnt]=wmv; E[cnt]=wmv*a.er1[idx];
        I[cnt]=e;
        cnt++;
      }
      r++;
    }
    c1max = wave_max(cnt);
    cmt=a.cm1[l]*6.f; gl=a.g1[l]; gv=gl*a.vl1[l];
    cur = pre[((size_t)(b<<10))*64 + l];
  } else {
    j2 = l&31; c = ((w-4)<<1) + (l>>5);
    #pragma unroll
    for (int q=0;q<4;q++){ A2[q]=0.f;B2[q]=0.f;W2[q]=0.f;E2[q]=0.f;I2[q]=0;
                           As2[q]=0.f;Bs2[q]=0.f;Ws2[q]=0.f;Es2[q]=0.f;Is2[q]=0; }
    { // main synapse (mk2): ranks == c (mod 8); 4 slots covers nnz<=32 exactly
      unsigned mm=0u;
      for (int e=0;e<32;e++)
        if (mask_at(a.mk2,md2,e*32+j2)!=0.f) mm |= (1u<<e);
      int r=0, cnt=0;
      while (mm){
        const int e=(int)__builtin_ctz(mm); mm&=mm-1;
        if ((r&7)==c && cnt<4){
          const int idx=e*32+j2;
          const float s=a.sg2[idx];
          A2[cnt]=-s*LOG2E; B2[cnt]=s*a.mu2[idx]*LOG2E;
          const float wmv=a.w2[idx];
          W2[cnt]=wmv; E2[cnt]=wmv*a.er2[idx];
          I2[cnt]=e;
          cnt++;
        }
        r++;
      }
    }
    { // sensory synapse (smk2), input-affine folded (verified R4)
      unsigned mm=0u;
      for (int e=0;e<32;e++)
        if (mask_at(a.smk2,mds2,e*32+j2)!=0.f) mm |= (1u<<e);
      int r=0, cnt=0;
      while (mm){
        const int e=(int)__builtin_ctz(mm); mm&=mm-1;
        if ((r&7)==c && cnt<4){
          const int idx=e*32+j2;
          const float s=a.ssg2[idx];
          float Aq=-s*LOG2E, Bq=s*a.smu2[idx]*LOG2E;
          const float wi=a.ow1[e]*a.iw2[e];
          const float ci=fmaf(a.ob1[e],a.iw2[e],a.ib2[e]);
          Bq=fmaf(Aq,ci,Bq); Aq*=wi;
          As2[cnt]=Aq; Bs2[cnt]=Bq;
          const float wmv=a.sw2[idx];
          Ws2[cnt]=wmv; Es2[cnt]=wmv*a.ser2[idx];
          Is2[cnt]=e;
          cnt++;
        }
        r++;
      }
    }
    cmt=a.cm2[j2]*6.f; gl=a.g2[j2]; gv=gl*a.vl2[j2];
  }

  float v1=0.f, v2=0.f;
  float bn=0.f, bdb=1.f;

  #pragma unroll 1
  for (int t=0;t<1026;t++){
    const bool l1act = L1g && (t<1024);
    const bool l2syn = (!L1g) && (t>=1) && (t<=1024);
    const bool l2u5  = (!L1g) && (t>=2);
    #pragma unroll
    for (int k=0;k<6;k++){
      const int buf = k&1;
      // ---------- pre-barrier: partial sums ----------
      if (l1act){
        float sn0=0.f,sn1=0.f,sd0=0.f,sd1=0.f;
        #pragma unroll
        for (int q=0;q<11;q++){            // branch-free common path
          const float vv=gather(v1, I[q]);
          const float z=fmaf(A[q],vv,B[q]);
          const float sg=frcp(1.f+fexp2(z));
          if (q&1){ sd1=fmaf(W[q],sg,sd1); sn1=fmaf(E[q],sg,sn1); }
          else    { sd0=fmaf(W[q],sg,sd0); sn0=fmaf(E[q],sg,sn0); }
        }
        if (c1max>11){                      // rare tail (nnz>44 in some column)
          #pragma unroll
          for (int q=11;q<16;q++){
            if (q<c1max){
              const float vv=gather(v1, I[q]);
              const float z=fmaf(A[q],vv,B[q]);
              const float sg=frcp(1.f+fexp2(z));
              sd0=fmaf(W[q],sg,sd0); sn0=fmaf(E[q],sg,sn0);
            }
          }
        }
        p1[buf][w][l]=make_float2(sn0+sn1, sd0+sd1);
      } else if (!L1g){
        const bool go = (k==0) ? l2u5 : l2syn;
        if (go){
          float sn=0.f, sd=0.f;
          #pragma unroll
          for (int q=0;q<4;q++){            // branch-free
            const float vv=gather(v2, I2[q]);
            const float z=fmaf(A2[q],vv,B2[q]);
            const float sg=frcp(1.f+fexp2(z));
            sd=fmaf(W2[q],sg,sd);
            sn=fmaf(E2[q],sg,sn);
          }
          p2[buf][c][j2]=make_float2(sn,sd);
        }
      }
      __syncthreads();
      // ---------- post-barrier: reductions + state update ----------
      if (l1act){
        if (k==0){
          bn = gv + cur.x;
          bdb = cmt + gl + cur.y + 1e-8f;
          if (t+1<1024) nxt = pre[((size_t)((b<<10)+t+1))*64 + l];
        }
        const float2 q0=p1[buf][0][l], q1=p1[buf][1][l], q2=p1[buf][2][l], q3=p1[buf][3][l];
        const float sn = (q0.x+q1.x)+(q2.x+q3.x);
        const float sd = (q0.y+q1.y)+(q2.y+q3.y);
        v1 = (fmaf(cmt,v1,bn)+sn) * frcp(bdb+sd);
        if (k==5){
          if (w==0) v1buf[l]=v1;
          cur=nxt;
        }
      } else if (!L1g){
        if (k==0){
          if (l2u5){
            float2 s0=p2[buf][0][j2], s1=p2[buf][1][j2], s2=p2[buf][2][j2], s3=p2[buf][3][j2];
            float2 s4=p2[buf][4][j2], s5=p2[buf][5][j2], s6=p2[buf][6][j2], s7=p2[buf][7][j2];
            const float sn=((s0.x+s1.x)+(s2.x+s3.x))+((s4.x+s5.x)+(s6.x+s7.x));
            const float sd=((s0.y+s1.y)+(s2.y+s3.y))+((s4.y+s5.y)+(s6.y+s7.y));
            v2 = (fmaf(cmt,v2,bn)+sn) * frcp(bdb+sd);   // finishes step t-2
          }
          if (l2syn){
            float ssn=0.f, ssd=0.f;
            #pragma unroll
            for (int q=0;q<4;q++){          // branch-free
              const float vb=v1buf[Is2[q]];              // v1(t-1)
              const float z=fmaf(As2[q],vb,Bs2[q]);
              const float sg=frcp(1.f+fexp2(z));
              ssd=fmaf(Ws2[q],sg,ssd);
              ssn=fmaf(Es2[q],sg,ssn);
            }
            pb[c][j2]=make_float2(ssn,ssd);
          }
        }
        if (k>=1 && l2syn){
          if (k==1){
            float2 s0=pb[0][j2], s1=pb[1][j2], s2=pb[2][j2], s3=pb[3][j2];
            float2 s4=pb[4][j2], s5=pb[5][j2], s6=pb[6][j2], s7=pb[7][j2];
            const float wns=((s0.x+s1.x)+(s2.x+s3.x))+((s4.x+s5.x)+(s6.x+s7.x));
            const float wds=((s0.y+s1.y)+(s2.y+s3.y))+((s4.y+s5.y)+(s6.y+s7.y));
            bn = gv + wns;
            bdb = cmt + gl + wds + 1e-8f;
          }
          float2 s0=p2[buf][0][j2], s1=p2[buf][1][j2], s2=p2[buf][2][j2], s3=p2[buf][3][j2];
          float2 s4=p2[buf][4][j2], s5=p2[buf][5][j2], s6=p2[buf][6][j2], s7=p2[buf][7][j2];
          const float sn=((s0.x+s1.x)+(s2.x+s3.x))+((s4.x+s5.x)+(s6.x+s7.x));
          const float sd=((s0.y+s1.y)+(s2.y+s3.y))+((s4.y+s5.y)+(s6.y+s7.y));
          v2 = (fmaf(cmt,v2,bn)+sn) * frcp(bdb+sd);     // unfold k-1 of step t-1
        }
      }
    }
  }

  if (w==4 && l<16){
    float o = fmaf(v2, a.ow2[l], a.ob2[l]) * a.fcw[l];
    o += __shfl_xor(o,1); o += __shfl_xor(o,2); o += __shfl_xor(o,4); o += __shfl_xor(o,8);
    if (l==0){
      const float z = o + a.fcb[0];
      a.out[b] = frcp(1.f + fexp2(-z*LOG2E));
    }
  }
}

// ================= fallback: R1 fused kernel (verified) =================
__global__ __launch_bounds__(256,1)
void ltc_fused(LtcArgs a)
{
  const int b=blockIdx.x, tid=threadIdx.x;
  __shared__ __align__(16) float xs[8192];
  __shared__ __align__(16) float v1s[2][64];
  __shared__ __align__(16) float v2s[2][32];
  __shared__ __align__(16) float u1s[8][32];
  __shared__ float cwts[184];
  __shared__ int cnt[8];

  {
    const float4* xg=(const float4*)(a.x + (size_t)b*8192);
    float4* xd=(float4*)xs;
    #pragma unroll
    for (int k=0;k<8;k++) xd[tid+256*k]=xg[tid+256*k];
  }
  if (tid<8) cnt[tid]=0;
  if (tid<64){ v1s[0][tid]=0.f; v1s[1][tid]=0.f; }
  if (tid<32){ v2s[0][tid]=0.f; v2s[1][tid]=0.f; }
  if (tid<12) cwts[tid]=a.c1w[tid];
  else if (tid<16)  cwts[tid]=a.c1b[tid-12];
  else if (tid<112) cwts[tid]=a.c2w[tid-16];
  else if (tid<120) cwts[tid]=a.c2b[tid-112];
  else if (tid<152) cwts[tid]=a.iw1[tid-120];
  else if (tid<184) cwts[tid]=a.ib1[tid-152];
  __syncthreads();

  scan_mask(a.mk1, 4096, tid, &cnt[0], &cnt[1]);
  scan_mask(a.smk1,2048, tid, &cnt[2], &cnt[3]);
  scan_mask(a.mk2, 1024, tid, &cnt[4], &cnt[5]);
  scan_mask(a.smk2,1024, tid, &cnt[6], &cnt[7]);
  __syncthreads();
  const int md1 =decide_mode(cnt[0],cnt[1],4096);
  const int mds1=decide_mode(cnt[2],cnt[3],2048);
  const int md2 =decide_mode(cnt[4],cnt[5],1024);
  const int mds2=decide_mode(cnt[6],cnt[7],1024);

  const int j1=tid>>2, ig1=tid&3;
  float Au[16],Bu[16],Wu[16],Eu[16];
  #pragma unroll
  for (int e=0;e<16;e++){
    const int i=16*ig1+e, idx=i*64+j1;
    const float s=a.sg1[idx];
    Au[e]=-s*LOG2E; Bu[e]=s*a.mu1[idx]*LOG2E;
    const float wm=a.w1[idx]*mask_at(a.mk1,md1,idx);
    Wu[e]=wm; Eu[e]=wm*a.er1[idx];
  }
  float As[8],Bs[8],Ws[8],Es[8];
  #pragma unroll
  for (int e=0;e<8;e++){
    const int i=8*ig1+e, idx=i*64+j1;
    const float s=a.ssg1[idx];
    As[e]=-s*LOG2E; Bs[e]=s*a.smu1[idx]*LOG2E;
    const float wm=a.sw1[idx]*mask_at(a.smk1,mds1,idx);
    Ws[e]=wm; Es[e]=wm*a.ser1[idx];
  }
  const float cmt1=a.cm1[j1]*6.f, gl1=a.g1[j1], gv1=gl1*a.vl1[j1];

  const int j2=tid>>3, ig2=tid&7;
  float A2[4],B2[4],W2[4],E2[4],A2s[4],B2s[4],W2s[4],E2s[4],Wi2[4],Ci2[4];
  #pragma unroll
  for (int e=0;e<4;e++){
    const int i=4*ig2+e, idx=i*32+j2;
    { const float s=a.sg2[idx];
      A2[e]=-s*LOG2E; B2[e]=s*a.mu2[idx]*LOG2E;
      const float wm=a.w2[idx]*mask_at(a.mk2,md2,idx);
      W2[e]=wm; E2[e]=wm*a.er2[idx]; }
    { const float s=a.ssg2[idx];
      A2s[e]=-s*LOG2E; B2s[e]=s*a.smu2[idx]*LOG2E;
      const float wm=a.sw2[idx]*mask_at(a.smk2,mds2,idx);
      W2s[e]=wm; E2s[e]=wm*a.ser2[idx]; }
    Wi2[e]=a.ow1[i]*a.iw2[i];
    Ci2[e]=fmaf(a.ob1[i],a.iw2[i],a.ib2[i]);
  }
  const float cmt2=a.cm2[j2]*6.f, gl2=a.g2[j2], gv2=gl2*a.vl2[j2];

  float vj1=0.f, vj2=0.f;
  int p1x=0, p2x=0;
  const int cf=tid&31, cc=cf>>2, cwp=cf&3, ctc=tid>>5;

  for (int t=0;t<1024;t++){
    if ((t&7)==0){
      const float* xr = &xs[(t+ctc)*8];
      float acc = cwts[112+cc];
      #pragma unroll
      for (int ci=0;ci<4;ci++){
        const float k10=cwts[ci*3], k11=cwts[ci*3+1], k12=cwts[ci*3+2], bb=cwts[12+ci];
        #pragma unroll
        for (int kk=0;kk<3;kk++){
          const int p=cwp+kk;
          float h = fmaf(k10,xr[p], fmaf(k11,xr[p+1], fmaf(k12,xr[p+2], bb)));
          h = fmaxf(h,0.f);
          acc = fmaf(cwts[16+(cc*4+ci)*3+kk], h, acc);
        }
      }
      u1s[ctc][cf] = fmaf(acc, cwts[120+cf], cwts[152+cf]);
      __syncthreads();
    }

    float wns=0.f, wds=0.f;
    {
      const float4* uv4=(const float4*)&u1s[t&7][8*ig1];
      float4 qa=uv4[0], qb=uv4[1];
      float uvv[8]={qa.x,qa.y,qa.z,qa.w,qb.x,qb.y,qb.z,qb.w};
      #pragma unroll
      for (int e=0;e<8;e++){
        float z=fmaf(As[e],uvv[e],Bs[e]);
        float sg=frcp(1.f+fexp2(z));
        wds=fmaf(Ws[e],sg,wds);
        wns=fmaf(Es[e],sg,wns);
      }
      wns += __shfl_xor(wns,1); wns += __shfl_xor(wns,2);
      wds += __shfl_xor(wds,1); wds += __shfl_xor(wds,2);
    }
    const float bn1 = gv1 + wns;
    const float bd1 = cmt1 + gl1 + wds + 1e-8f;

    #pragma unroll
    for (int k=0;k<6;k++){
      const float4* vv4=(const float4*)&v1s[p1x][16*ig1];
      float4 q0=vv4[0], q1=vv4[1], q2=vv4[2], q3=vv4[3];
      float vi[16]={q0.x,q0.y,q0.z,q0.w,q1.x,q1.y,q1.z,q1.w,
                    q2.x,q2.y,q2.z,q2.w,q3.x,q3.y,q3.z,q3.w};
      float sn=0.f, sd=0.f;
      #pragma unroll
      for (int e=0;e<16;e++){
        float z=fmaf(Au[e],vi[e],Bu[e]);
        float sg=frcp(1.f+fexp2(z));
        sd=fmaf(Wu[e],sg,sd);
        sn=fmaf(Eu[e],sg,sn);
      }
      sn += __shfl_xor(sn,1); sn += __shfl_xor(sn,2);
      sd += __shfl_xor(sd,1); sd += __shfl_xor(sd,2);
      vj1 = (fmaf(cmt1,vj1,bn1)+sn) * frcp(bd1+sd);
      p1x ^= 1;
      if (ig1==0) v1s[p1x][j1]=vj1;
      __syncthreads();
    }

    float wns2=0.f, wds2=0.f;
    {
      const float4* vf4=(const float4*)&v1s[p1x][4*ig2];
      float4 vf=vf4[0];
      float vin[4]={vf.x,vf.y,vf.z,vf.w};
      #pragma unroll
      for (int e=0;e<4;e++){
        float u2=fmaf(vin[e],Wi2[e],Ci2[e]);
        float z=fmaf(A2s[e],u2,B2s[e]);
        float sg=frcp(1.f+fexp2(z));
        wds2=fmaf(W2s[e],sg,wds2);
        wns2=fmaf(E2s[e],sg,wns2);
      }
      wns2 += __shfl_xor(wns2,1); wns2 += __shfl_xor(wns2,2); wns2 += __shfl_xor(wns2,4);
      wds2 += __shfl_xor(wds2,1); wds2 += __shfl_xor(wds2,2); wds2 += __shfl_xor(wds2,4);
    }
    const float bn2 = gv2 + wns2;
    const float bd2 = cmt2 + gl2 + wds2 + 1e-8f;

    #pragma unroll
    for (int k=0;k<6;k++){
      const float4* vv4=(const float4*)&v2s[p2x][4*ig2];
      float4 q=vv4[0];
      float vi[4]={q.x,q.y,q.z,q.w};
      float sn=0.f, sd=0.f;
      #pragma unroll
      for (int e=0;e<4;e++){
        float z=fmaf(A2[e],vi[e],B2[e]);
        float sg=frcp(1.f+fexp2(z));
        sd=fmaf(W2[e],sg,sd);
        sn=fmaf(E2[e],sg,sn);
      }
      sn += __shfl_xor(sn,1); sn += __shfl_xor(sn,2); sn += __shfl_xor(sn,4);
      sd += __shfl_xor(sd,1); sd += __shfl_xor(sd,2); sd += __shfl_xor(sd,4);
      vj2 = (fmaf(cmt2,vj2,bn2)+sn) * frcp(bd2+sd);
      p2x ^= 1;
      if (ig2==0) v2s[p2x][j2]=vj2;
      __syncthreads();
    }
  }

  if (tid<16){
    float o = fmaf(v2s[p2x][tid], a.ow2[tid], a.ob2[tid]) * a.fcw[tid];
    o += __shfl_xor(o,1); o += __shfl_xor(o,2); o += __shfl_xor(o,4); o += __shfl_xor(o,8);
    if (tid==0){
      float z = o + a.fcb[0];
      a.out[b] = frcp(1.f + fexp2(-z*LOG2E));
    }
  }
}

extern "C" void kernel_launch(void* const* d_in, const int* in_sizes, int n_in,
                              void* d_out, int out_size, void* d_ws, size_t ws_size,
                              hipStream_t stream)
{
  (void)out_size;
  int o[41];
  for (int i=0;i<41;i++) o[i]=i;
  if (n_in>=41 && in_sizes[20]!=4096){
    for (int i=0;i<15;i++) o[5+i]=5+i;
    o[20]=37; o[21]=38;
    for (int i=0;i<15;i++) o[22+i]=20+i;
    o[37]=39; o[38]=40;
    o[39]=35; o[40]=36;
  }
  const float* F[41];
  for (int i=0;i<41;i++) F[i]=(const float*)d_in[o[i]];
  LtcArgs a;
  a.x=F[0]; a.c1w=F[1]; a.c1b=F[2]; a.c2w=F[3]; a.c2b=F[4];
  a.g1=F[5]; a.vl1=F[6]; a.cm1=F[7]; a.sg1=F[8]; a.mu1=F[9]; a.w1=F[10]; a.er1=F[11];
  a.ssg1=F[12]; a.smu1=F[13]; a.sw1=F[14]; a.ser1=F[15];
  a.iw1=F[16]; a.ib1=F[17]; a.ow1=F[18]; a.ob1=F[19];
  a.mk1=(const void*)d_in[o[20]]; a.smk1=(const void*)d_in[o[21]];
  a.g2=F[22]; a.vl2=F[23]; a.cm2=F[24]; a.sg2=F[25]; a.mu2=F[26]; a.w2=F[27]; a.er2=F[28];
  a.ssg2=F[29]; a.smu2=F[30]; a.sw2=F[31]; a.ser2=F[32];
  a.iw2=F[33]; a.ib2=F[34]; a.ow2=F[35]; a.ob2=F[36];
  a.mk2=(const void*)d_in[o[37]]; a.smk2=(const void*)d_in[o[38]];
  a.fcw=F[39]; a.fcb=F[40];
  a.out=(float*)d_out;

  const size_t need = 256 + (size_t)256*1024*64*sizeof(float2);
  if (ws_size >= need){
    int* hdr = (int*)d_ws;
    float2* pre = (float2*)((char*)d_ws + 256);
    ltc_modes<<<dim3(1),dim3(256),0,stream>>>(a.mk1,a.smk1,a.mk2,a.smk2,hdr);
    ltc_pre<<<dim3(256,16),dim3(256),0,stream>>>(a,hdr,pre);
    ltc_scan<<<dim3(256),dim3(512),0,stream>>>(a,pre,hdr);
  } else {
    ltc_fused<<<dim3(256),dim3(256),0,stream>>>(a);
  }
}